// Round 6
// baseline (529.952 us; speedup 1.0000x reference)
//
#include <hip/hip_runtime.h>
#include <math.h>

// SSIM loss, fused single pass.
// R8 = R6 (scalar fp32 — R7 showed v_pk_f32 is NOT 2x on gfx950: the 157 TF
// fp32 peak IS the scalar rate; packed halves issue but not pipe time and
// regressed 25%) + REGISTER PREFETCH of the next chunk's 22 input rows
// during the current chunk's compute. R6's per-chunk structure exposed
// ~200-900cy of global-load latency on the critical path 9x per block
// (measured 168us vs ~65us VALU-pipe floor). Prefetch regs are 22 NAMED
// scalars (R2/R3: float[11] arrays fail SROA -> scratch).
// __launch_bounds__(256,6): regalloc <=85 VGPR so LDS-limited 6 blocks/CU
// is preserved (prefetch raises VGPR ~48 -> ~75).
// R6: 4-channel algebraic reduction (u=x+y, v=x-y basis; SSIM needs only
//     mxx+myy): 4mxmy=MU^2-MV^2, 2(mx^2+my^2)=MU^2+MV^2, 4mxy=MUU-MVV,
//     2(mxx+myy)=MUU+MVV. NCHUNKY=3 for occupancy.
// R4 lesson kept: ring buffers as NAMED scalars (macro-unrolled ring phases).

#define KS    11
#define IMG_H 256
#define IMG_W 256
#define PADW  268          // tap reads up to col 265, no guard needed
#define OUTD  246
#define NIMG  496
#define OUT_ROWS 82        // 3 y-chunks x 82 = 246
#define NCHUNKY  3
#define NCHUNKS  9         // ceil((82+10)/11)
#define C1F   0.0001f
#define C2F   0.0009f

// 11-tap gaussian (sigma=1.5), normalized; computed in double offline.
__device__ constexpr float GW[KS] = {
    0.00102838f, 0.00759876f, 0.03600077f, 0.10936068f, 0.21300554f,
    0.26601173f,
    0.21300554f, 0.10936068f, 0.03600077f, 0.00759876f, 0.00102838f
};

// prefetch row r of chunk starting at jjn into named regs xp##r / yp##r
#define LOADC(r)                                                           \
  do {                                                                     \
    int row_ = out_r0 + jjn + r;                                           \
    row_ = min(row_, IMG_H - 1);   /* clamped rows feed discarded outs */  \
    xp##r = Xi[(row_ << 8) + tid];                                         \
    yp##r = Yi[(row_ << 8) + tid];                                         \
  } while (0)

// write prefetched row r to LDS in (u,v) = (x+y, x-y) basis
#define WRITEC(r)                                                          \
  rowbuf[r][tid] = make_float2(xp##r + yp##r, xp##r - yp##r);

// horizontal blur of row K of the staged tile, result -> ring slot C
// channels: u, v, u^2, v^2  (squares reuse wu/wv: 6 VALU per tap)
#define HBLUR_STORE(K, C)                                                  \
  do {                                                                     \
    float hu = 0.f, hv = 0.f, huu = 0.f, hvv = 0.f;                        \
    _Pragma("unroll")                                                      \
    for (int t = 0; t < KS; ++t) {                                         \
      const float2 val = rowbuf[K][tid + t];                               \
      const float w  = GW[t];                                              \
      const float wu = w * val.x, wv = w * val.y;                          \
      hu  += wu;          hv  += wv;                                       \
      huu += wu * val.x;  hvv += wv * val.y;                               \
    }                                                                      \
    su##C = hu; sv##C = hv; suu##C = huu; svv##C = hvv;                    \
  } while (0)

#define VDOT(M, t0,t1,t2,t3,t4,t5,t6,t7,t8,t9,t10)                         \
  (GW[0]*M##t0 + GW[1]*M##t1 + GW[2]*M##t2 + GW[3]*M##t3 + GW[4]*M##t4     \
 + GW[5]*M##t5 + GW[6]*M##t6 + GW[7]*M##t7 + GW[8]*M##t8 + GW[9]*M##t9     \
 + GW[10]*M##t10)

// one ring phase: h-blur row jj+K into slot K (== t10), then if a full 11-row
// window is resident, v-blur (taps read slots (K+1+t)%11 = t0..t10) + SSIM.
// Reconstruction (A=MU^2, B=MV^2):
//   2 mx my  = (A-B)/2      mx^2+my^2   = (A+B)/2
//   2 m(xy)  = (MUU-MVV)/2  m(xx)+m(yy) = (MUU+MVV)/2
#define STEP(K, t0,t1,t2,t3,t4,t5,t6,t7,t8,t9,t10)                         \
  HBLUR_STORE(K, t10);                                                     \
  {                                                                        \
    const int jrow = jj + K;                                               \
    const int irow = jrow - (KS - 1);                                      \
    if (jrow >= KS - 1 && irow < OUT_ROWS) {   /* wave-uniform */          \
      const float MU  = VDOT(su,  t0,t1,t2,t3,t4,t5,t6,t7,t8,t9,t10);     \
      const float MV  = VDOT(sv,  t0,t1,t2,t3,t4,t5,t6,t7,t8,t9,t10);     \
      const float MUU = VDOT(suu, t0,t1,t2,t3,t4,t5,t6,t7,t8,t9,t10);     \
      const float MVV = VDOT(svv, t0,t1,t2,t3,t4,t5,t6,t7,t8,t9,t10);     \
      const float A   = MU * MU;                                           \
      const float B   = MV * MV;                                           \
      const float dAB = A - B;            /* = 4 mx my          */         \
      const float sAB = A + B;            /* = 2(mx^2+my^2)     */         \
      const float dM  = MUU - MVV;        /* = 4 m(xy)          */         \
      const float sM  = MUU + MVV;        /* = 2(m(xx)+m(yy))   */         \
      const float n1 = 0.5f * dAB + C1F;        /* 2 mx my + C1 */         \
      const float d1 = 0.5f * sAB + C1F;        /* mx^2+my^2+C1 */         \
      const float n2 = 0.5f * (dM - dAB) + C2F; /* 2 cov   + C2 */         \
      const float d2 = 0.5f * (sM - sAB) + C2F; /* vx + vy + C2 */         \
      const float num = n1 * n2;                                           \
      const float den = d1 * d2;                                           \
      ssum += active ? num * __builtin_amdgcn_rcpf(den) : 0.f;             \
    }                                                                      \
  }

__global__ __launch_bounds__(256, 6)
void ssim_fused_kernel(const float* __restrict__ X, const float* __restrict__ Y,
                       double* __restrict__ accum) {
    __shared__ float2 rowbuf[KS][PADW];
    __shared__ float  wsum[4];

    const int img    = blockIdx.x;
    const int out_r0 = blockIdx.y * OUT_ROWS;
    const int tid    = threadIdx.x;
    const bool active = (tid < OUTD);

    const float* Xi = X + (size_t)img * (IMG_H * IMG_W);
    const float* Yi = Y + (size_t)img * (IMG_H * IMG_W);

    // 44 named ring registers (slot = local_row % 11)
    float su0=0,su1=0,su2=0,su3=0,su4=0,su5=0,su6=0,su7=0,su8=0,su9=0,su10=0;
    float sv0=0,sv1=0,sv2=0,sv3=0,sv4=0,sv5=0,sv6=0,sv7=0,sv8=0,sv9=0,sv10=0;
    float suu0=0,suu1=0,suu2=0,suu3=0,suu4=0,suu5=0,suu6=0,suu7=0,suu8=0,suu9=0,suu10=0;
    float svv0=0,svv1=0,svv2=0,svv3=0,svv4=0,svv5=0,svv6=0,svv7=0,svv8=0,svv9=0,svv10=0;

    // 22 named prefetch registers (next chunk's raw rows)
    float xp0,xp1,xp2,xp3,xp4,xp5,xp6,xp7,xp8,xp9,xp10;
    float yp0,yp1,yp2,yp3,yp4,yp5,yp6,yp7,yp8,yp9,yp10;

    float ssum = 0.0f;

    // prefetch chunk 0
    {
        const int jjn = 0;
        LOADC(0); LOADC(1); LOADC(2); LOADC(3); LOADC(4); LOADC(5);
        LOADC(6); LOADC(7); LOADC(8); LOADC(9); LOADC(10);
    }

    for (int c = 0; c < NCHUNKS; ++c) {
        const int jj = c * KS;
        __syncthreads();              // prev chunk's rowbuf reads complete
        // drain prefetched regs into LDS (vmcnt wait is a chunk old -> landed)
        WRITEC(0); WRITEC(1); WRITEC(2); WRITEC(3); WRITEC(4); WRITEC(5);
        WRITEC(6); WRITEC(7); WRITEC(8); WRITEC(9); WRITEC(10);
        __syncthreads();              // rowbuf visible to all

        // issue next chunk's loads; latency hides under the 11 STEPs below
        if (c + 1 < NCHUNKS) {
            const int jjn = jj + KS;
            LOADC(0); LOADC(1); LOADC(2); LOADC(3); LOADC(4); LOADC(5);
            LOADC(6); LOADC(7); LOADC(8); LOADC(9); LOADC(10);
        }

        STEP(0,  1,2,3,4,5,6,7,8,9,10,0)
        STEP(1,  2,3,4,5,6,7,8,9,10,0,1)
        STEP(2,  3,4,5,6,7,8,9,10,0,1,2)
        STEP(3,  4,5,6,7,8,9,10,0,1,2,3)
        STEP(4,  5,6,7,8,9,10,0,1,2,3,4)
        STEP(5,  6,7,8,9,10,0,1,2,3,4,5)
        STEP(6,  7,8,9,10,0,1,2,3,4,5,6)
        STEP(7,  8,9,10,0,1,2,3,4,5,6,7)
        STEP(8,  9,10,0,1,2,3,4,5,6,7,8)
        STEP(9,  10,0,1,2,3,4,5,6,7,8,9)
        STEP(10, 0,1,2,3,4,5,6,7,8,9,10)
    }

    // block reduction
    #pragma unroll
    for (int off = 32; off > 0; off >>= 1)
        ssum += __shfl_down(ssum, off);
    const int lane = tid & 63, wid = tid >> 6;
    if (lane == 0) wsum[wid] = ssum;
    __syncthreads();
    if (tid == 0) {
        const double s = (double)wsum[0] + (double)wsum[1]
                       + (double)wsum[2] + (double)wsum[3];
        atomicAdd(accum, s);
    }
}

__global__ void ssim_finalize_kernel(const double* __restrict__ accum,
                                     float* __restrict__ out) {
    const double cnt = (double)NIMG * OUTD * OUTD;   // 30,015,936
    out[0] = (float)(1.0 - accum[0] / cnt);
}

extern "C" void kernel_launch(void* const* d_in, const int* in_sizes, int n_in,
                              void* d_out, int out_size, void* d_ws, size_t ws_size,
                              hipStream_t stream) {
    (void)in_sizes; (void)n_in; (void)out_size; (void)ws_size;
    const float* X = (const float*)d_in[0];
    const float* Y = (const float*)d_in[1];
    float* out = (float*)d_out;
    double* acc = (double*)d_ws;

    hipMemsetAsync(d_ws, 0, sizeof(double), stream);

    dim3 grid(NIMG, NCHUNKY);
    hipLaunchKernelGGL(ssim_fused_kernel, grid, dim3(256), 0, stream, X, Y, acc);
    hipLaunchKernelGGL(ssim_finalize_kernel, dim3(1), dim3(1), 0, stream, acc, out);
}

// Round 7
// 325.594 us; speedup vs baseline: 1.6276x; 1.6276x over previous
//
#include <hip/hip_runtime.h>
#include <math.h>

// SSIM loss, fused single pass.
// R9 = R8 with __launch_bounds__(256,4). R8's (256,6) capped regalloc at
// ~85 VGPR; the allocator spilled the 22 prefetch + 44 ring scalars to
// scratch (VGPR_Count 40, WRITE_SIZE 46KB->537MB, FETCH +304MB, 2.1x
// regression). (256,4) caps at 128 VGPR: the ~90-100 live range fits, and
// the 4-block/CU occupancy ceiling (16 waves) is above R6's measured
// time-average occupancy (39% ~= 12.5 waves) so nothing real is lost.
// R8: REGISTER PREFETCH of next chunk's 22 rows during current chunk's
//     compute -- R6 exposed ~200-900cy global-load latency 9x per block
//     (measured 168us vs ~65us VALU-pipe floor).
// R7 lesson: v_pk_f32 is NOT 2x on gfx950 (157TF fp32 peak IS scalar rate).
// R6: 4-channel algebraic reduction (u=x+y, v=x-y basis; SSIM needs only
//     mxx+myy): 4mxmy=MU^2-MV^2, 2(mx^2+my^2)=MU^2+MV^2, 4mxy=MUU-MVV,
//     2(mxx+myy)=MUU+MVV. NCHUNKY=3 for occupancy.
// R4 lesson: ring buffers as NAMED scalars (arrays fail SROA -> scratch).

#define KS    11
#define IMG_H 256
#define IMG_W 256
#define PADW  268          // tap reads up to col 265, no guard needed
#define OUTD  246
#define NIMG  496
#define OUT_ROWS 82        // 3 y-chunks x 82 = 246
#define NCHUNKY  3
#define NCHUNKS  9         // ceil((82+10)/11)
#define C1F   0.0001f
#define C2F   0.0009f

// 11-tap gaussian (sigma=1.5), normalized; computed in double offline.
__device__ constexpr float GW[KS] = {
    0.00102838f, 0.00759876f, 0.03600077f, 0.10936068f, 0.21300554f,
    0.26601173f,
    0.21300554f, 0.10936068f, 0.03600077f, 0.00759876f, 0.00102838f
};

// prefetch row r of chunk starting at jjn into named regs xp##r / yp##r
#define LOADC(r)                                                           \
  do {                                                                     \
    int row_ = out_r0 + jjn + r;                                           \
    row_ = min(row_, IMG_H - 1);   /* clamped rows feed discarded outs */  \
    xp##r = Xi[(row_ << 8) + tid];                                         \
    yp##r = Yi[(row_ << 8) + tid];                                         \
  } while (0)

// write prefetched row r to LDS in (u,v) = (x+y, x-y) basis
#define WRITEC(r)                                                          \
  rowbuf[r][tid] = make_float2(xp##r + yp##r, xp##r - yp##r);

// horizontal blur of row K of the staged tile, result -> ring slot C
// channels: u, v, u^2, v^2  (squares reuse wu/wv: 6 VALU per tap)
#define HBLUR_STORE(K, C)                                                  \
  do {                                                                     \
    float hu = 0.f, hv = 0.f, huu = 0.f, hvv = 0.f;                        \
    _Pragma("unroll")                                                      \
    for (int t = 0; t < KS; ++t) {                                         \
      const float2 val = rowbuf[K][tid + t];                               \
      const float w  = GW[t];                                              \
      const float wu = w * val.x, wv = w * val.y;                          \
      hu  += wu;          hv  += wv;                                       \
      huu += wu * val.x;  hvv += wv * val.y;                               \
    }                                                                      \
    su##C = hu; sv##C = hv; suu##C = huu; svv##C = hvv;                    \
  } while (0)

#define VDOT(M, t0,t1,t2,t3,t4,t5,t6,t7,t8,t9,t10)                         \
  (GW[0]*M##t0 + GW[1]*M##t1 + GW[2]*M##t2 + GW[3]*M##t3 + GW[4]*M##t4     \
 + GW[5]*M##t5 + GW[6]*M##t6 + GW[7]*M##t7 + GW[8]*M##t8 + GW[9]*M##t9     \
 + GW[10]*M##t10)

// one ring phase: h-blur row jj+K into slot K (== t10), then if a full 11-row
// window is resident, v-blur (taps read slots (K+1+t)%11 = t0..t10) + SSIM.
// Reconstruction (A=MU^2, B=MV^2):
//   2 mx my  = (A-B)/2      mx^2+my^2   = (A+B)/2
//   2 m(xy)  = (MUU-MVV)/2  m(xx)+m(yy) = (MUU+MVV)/2
#define STEP(K, t0,t1,t2,t3,t4,t5,t6,t7,t8,t9,t10)                         \
  HBLUR_STORE(K, t10);                                                     \
  {                                                                        \
    const int jrow = jj + K;                                               \
    const int irow = jrow - (KS - 1);                                      \
    if (jrow >= KS - 1 && irow < OUT_ROWS) {   /* wave-uniform */          \
      const float MU  = VDOT(su,  t0,t1,t2,t3,t4,t5,t6,t7,t8,t9,t10);     \
      const float MV  = VDOT(sv,  t0,t1,t2,t3,t4,t5,t6,t7,t8,t9,t10);     \
      const float MUU = VDOT(suu, t0,t1,t2,t3,t4,t5,t6,t7,t8,t9,t10);     \
      const float MVV = VDOT(svv, t0,t1,t2,t3,t4,t5,t6,t7,t8,t9,t10);     \
      const float A   = MU * MU;                                           \
      const float B   = MV * MV;                                           \
      const float dAB = A - B;            /* = 4 mx my          */         \
      const float sAB = A + B;            /* = 2(mx^2+my^2)     */         \
      const float dM  = MUU - MVV;        /* = 4 m(xy)          */         \
      const float sM  = MUU + MVV;        /* = 2(m(xx)+m(yy))   */         \
      const float n1 = 0.5f * dAB + C1F;        /* 2 mx my + C1 */         \
      const float d1 = 0.5f * sAB + C1F;        /* mx^2+my^2+C1 */         \
      const float n2 = 0.5f * (dM - dAB) + C2F; /* 2 cov   + C2 */         \
      const float d2 = 0.5f * (sM - sAB) + C2F; /* vx + vy + C2 */         \
      const float num = n1 * n2;                                           \
      const float den = d1 * d2;                                           \
      ssum += active ? num * __builtin_amdgcn_rcpf(den) : 0.f;             \
    }                                                                      \
  }

__global__ __launch_bounds__(256, 4)
void ssim_fused_kernel(const float* __restrict__ X, const float* __restrict__ Y,
                       double* __restrict__ accum) {
    __shared__ float2 rowbuf[KS][PADW];
    __shared__ float  wsum[4];

    const int img    = blockIdx.x;
    const int out_r0 = blockIdx.y * OUT_ROWS;
    const int tid    = threadIdx.x;
    const bool active = (tid < OUTD);

    const float* Xi = X + (size_t)img * (IMG_H * IMG_W);
    const float* Yi = Y + (size_t)img * (IMG_H * IMG_W);

    // 44 named ring registers (slot = local_row % 11)
    float su0=0,su1=0,su2=0,su3=0,su4=0,su5=0,su6=0,su7=0,su8=0,su9=0,su10=0;
    float sv0=0,sv1=0,sv2=0,sv3=0,sv4=0,sv5=0,sv6=0,sv7=0,sv8=0,sv9=0,sv10=0;
    float suu0=0,suu1=0,suu2=0,suu3=0,suu4=0,suu5=0,suu6=0,suu7=0,suu8=0,suu9=0,suu10=0;
    float svv0=0,svv1=0,svv2=0,svv3=0,svv4=0,svv5=0,svv6=0,svv7=0,svv8=0,svv9=0,svv10=0;

    // 22 named prefetch registers (next chunk's raw rows)
    float xp0,xp1,xp2,xp3,xp4,xp5,xp6,xp7,xp8,xp9,xp10;
    float yp0,yp1,yp2,yp3,yp4,yp5,yp6,yp7,yp8,yp9,yp10;

    float ssum = 0.0f;

    // prefetch chunk 0
    {
        const int jjn = 0;
        LOADC(0); LOADC(1); LOADC(2); LOADC(3); LOADC(4); LOADC(5);
        LOADC(6); LOADC(7); LOADC(8); LOADC(9); LOADC(10);
    }

    for (int c = 0; c < NCHUNKS; ++c) {
        const int jj = c * KS;
        __syncthreads();              // prev chunk's rowbuf reads complete
        // drain prefetched regs into LDS (vmcnt wait is a chunk old -> landed)
        WRITEC(0); WRITEC(1); WRITEC(2); WRITEC(3); WRITEC(4); WRITEC(5);
        WRITEC(6); WRITEC(7); WRITEC(8); WRITEC(9); WRITEC(10);
        __syncthreads();              // rowbuf visible to all

        // issue next chunk's loads; latency hides under the 11 STEPs below
        if (c + 1 < NCHUNKS) {
            const int jjn = jj + KS;
            LOADC(0); LOADC(1); LOADC(2); LOADC(3); LOADC(4); LOADC(5);
            LOADC(6); LOADC(7); LOADC(8); LOADC(9); LOADC(10);
        }

        STEP(0,  1,2,3,4,5,6,7,8,9,10,0)
        STEP(1,  2,3,4,5,6,7,8,9,10,0,1)
        STEP(2,  3,4,5,6,7,8,9,10,0,1,2)
        STEP(3,  4,5,6,7,8,9,10,0,1,2,3)
        STEP(4,  5,6,7,8,9,10,0,1,2,3,4)
        STEP(5,  6,7,8,9,10,0,1,2,3,4,5)
        STEP(6,  7,8,9,10,0,1,2,3,4,5,6)
        STEP(7,  8,9,10,0,1,2,3,4,5,6,7)
        STEP(8,  9,10,0,1,2,3,4,5,6,7,8)
        STEP(9,  10,0,1,2,3,4,5,6,7,8,9)
        STEP(10, 0,1,2,3,4,5,6,7,8,9,10)
    }

    // block reduction
    #pragma unroll
    for (int off = 32; off > 0; off >>= 1)
        ssum += __shfl_down(ssum, off);
    const int lane = tid & 63, wid = tid >> 6;
    if (lane == 0) wsum[wid] = ssum;
    __syncthreads();
    if (tid == 0) {
        const double s = (double)wsum[0] + (double)wsum[1]
                       + (double)wsum[2] + (double)wsum[3];
        atomicAdd(accum, s);
    }
}

__global__ void ssim_finalize_kernel(const double* __restrict__ accum,
                                     float* __restrict__ out) {
    const double cnt = (double)NIMG * OUTD * OUTD;   // 30,015,936
    out[0] = (float)(1.0 - accum[0] / cnt);
}

extern "C" void kernel_launch(void* const* d_in, const int* in_sizes, int n_in,
                              void* d_out, int out_size, void* d_ws, size_t ws_size,
                              hipStream_t stream) {
    (void)in_sizes; (void)n_in; (void)out_size; (void)ws_size;
    const float* X = (const float*)d_in[0];
    const float* Y = (const float*)d_in[1];
    float* out = (float*)d_out;
    double* acc = (double*)d_ws;

    hipMemsetAsync(d_ws, 0, sizeof(double), stream);

    dim3 grid(NIMG, NCHUNKY);
    hipLaunchKernelGGL(ssim_fused_kernel, grid, dim3(256), 0, stream, X, Y, acc);
    hipLaunchKernelGGL(ssim_finalize_kernel, dim3(1), dim3(1), 0, stream, acc, out);
}